// Round 5
// baseline (112.223 us; speedup 1.0000x reference)
//
#include <hip/hip_runtime.h>

#define IN_CH 32
#define OUT_CH 128
#define BSHIFT 7
#define BW 128          // nodes per bucket
#define NB_P 1024       // >= ceil(100000/128)=782
#define PCHUNK 2048     // edges per partition block
#define ACH 2048        // edges per k_agg sort-chunk

// ---------------------------------------------------------------------------
// A: init per-bucket slab cursors: gcursor[b] = b*cap.
// ---------------------------------------------------------------------------
__global__ __launch_bounds__(512) void k_init(int* __restrict__ gcursor, int cap) {
  int i = blockIdx.x * 512 + threadIdx.x;
  if (i < NB_P) gcursor[i] = i * cap;
}

// ---------------------------------------------------------------------------
// C: partition with LDS reorder (unchanged, proven)
// ---------------------------------------------------------------------------
__global__ __launch_bounds__(256) void k_partition(const int* __restrict__ src,
                                                   const int* __restrict__ dst,
                                                   int* __restrict__ gcursor,
                                                   unsigned* __restrict__ part,
                                                   int E) {
  __shared__ int cnt[NB_P];
  __shared__ int lbase[NB_P];
  __shared__ int cur[NB_P];
  __shared__ int gbase[NB_P];
  __shared__ int ssum[256];
  __shared__ unsigned sval[PCHUNK];
  __shared__ int sadr[PCHUNK];
  const int t = threadIdx.x;
  const int base = blockIdx.x * PCHUNK;
  const int m = min(PCHUNK, E - base);
  for (int i = t; i < NB_P; i += 256) cnt[i] = 0;
  __syncthreads();
  int dl[8], sl[8];
#pragma unroll
  for (int u = 0; u < 8; ++u) {
    int i = t + 256 * u;
    dl[u] = -1;
    if (i < m) {
      dl[u] = dst[base + i];
      sl[u] = src[base + i];
      atomicAdd(&cnt[dl[u] >> BSHIFT], 1);
    }
  }
  __syncthreads();
  const int b4 = t * 4;
  int c0 = cnt[b4], c1 = cnt[b4 + 1], c2 = cnt[b4 + 2], c3 = cnt[b4 + 3];
  ssum[t] = c0 + c1 + c2 + c3;
  __syncthreads();
  for (int o = 1; o < 256; o <<= 1) {
    int a = (t >= o) ? ssum[t - o] : 0;
    __syncthreads();
    ssum[t] += a;
    __syncthreads();
  }
  int run = (t == 0) ? 0 : ssum[t - 1];
  lbase[b4] = run; cur[b4] = run; run += c0;
  lbase[b4 + 1] = run; cur[b4 + 1] = run; run += c1;
  lbase[b4 + 2] = run; cur[b4 + 2] = run; run += c2;
  lbase[b4 + 3] = run; cur[b4 + 3] = run;
  __syncthreads();
  for (int i = t; i < NB_P; i += 256)
    gbase[i] = cnt[i] ? atomicAdd(&gcursor[i], cnt[i]) : 0;
  __syncthreads();
#pragma unroll
  for (int u = 0; u < 8; ++u) {
    if (dl[u] >= 0) {
      int b = dl[u] >> BSHIFT;
      int p = atomicAdd(&cur[b], 1);
      sval[p] = ((unsigned)sl[u] << BSHIFT) | (unsigned)(dl[u] & (BW - 1));
      sadr[p] = gbase[b] + (p - lbase[b]);
    }
  }
  __syncthreads();
  for (int i = t; i < m; i += 256) part[sadr[i]] = sval[i];
}

// ---------------------------------------------------------------------------
// D: sorted owner-exclusive aggregation; 512 threads; subgroup owns 8 bins.
//    NEW: bins processed as 4 PAIRS with interleaved 8-wide gather batches
//    -> 16 load-instructions in flight per wave (was 8), halving the count
//    of serial latency stalls. __launch_bounds__(512,8) pins VGPR<=64 so
//    occupancy stays 8 waves/SIMD (4 blocks/CU resident; grid 782 fits).
// ---------------------------------------------------------------------------
__global__ __launch_bounds__(512, 8) void k_agg(const float* __restrict__ x,
                                                const unsigned* __restrict__ part,
                                                const int* __restrict__ gcursor,
                                                float* __restrict__ agg, int n,
                                                int cap) {
  __shared__ float sacc[BW * IN_CH];   // 16 KB, owner-exclusive RMW
  __shared__ int sdeg[BW];
  __shared__ int hcnt[BW];
  __shared__ int ssc[BW];
  __shared__ int boff[BW + 1];
  __shared__ int cur[BW];
  __shared__ unsigned sval[ACH];       // 8 KB sorted chunk
  const int t = threadIdx.x;
  const int sub = t >> 5;   // 16 subgroups of 32 lanes
  const int k = t & 31;     // channel
#pragma unroll
  for (int i = 0; i < 8; ++i) sacc[t + 512 * i] = 0.0f;
  if (t < BW) sdeg[t] = 0;
  __syncthreads();
  const int b = blockIdx.x;
  const int e0 = b * cap;
  const int cn = gcursor[b] - e0;

  for (int base = 0; base < cn; base += ACH) {
    const int m = min(ACH, cn - base);
    if (t < BW) hcnt[t] = 0;
    __syncthreads();
    unsigned ev[4];
#pragma unroll
    for (int u = 0; u < 4; ++u) {
      int i = t + 512 * u;
      ev[u] = 0xFFFFFFFFu;
      if (i < m) {
        ev[u] = part[e0 + base + i];
        atomicAdd(&hcnt[ev[u] & (BW - 1)], 1);
      }
    }
    __syncthreads();
    if (t < BW) ssc[t] = hcnt[t];
    __syncthreads();
    for (int o = 1; o < BW; o <<= 1) {
      int a = (t >= o && t < BW) ? ssc[t - o] : 0;
      __syncthreads();
      if (t < BW) ssc[t] += a;
      __syncthreads();
    }
    if (t < BW) {
      int excl = (t == 0) ? 0 : ssc[t - 1];
      boff[t] = excl;
      cur[t] = excl;
      sdeg[t] += hcnt[t];
    }
    if (t == 0) boff[BW] = m;
    __syncthreads();
#pragma unroll
    for (int u = 0; u < 4; ++u) {
      if (ev[u] != 0xFFFFFFFFu) {
        int dl = ev[u] & (BW - 1);
        int p = atomicAdd(&cur[dl], 1);
        sval[p] = ev[u];
      }
    }
    __syncthreads();
    // owner-exclusive segmented reduction over 4 bin-PAIRS per subgroup:
    // both runs of a pair advance together -> 2x outstanding loads.
    for (int pp = 0; pp < 4; ++pp) {
      const int dA = (sub << 3) + 2 * pp;
      const int dB = dA + 1;
      int jA = boff[dA];
      const int jeA = boff[dA + 1];
      int jB = boff[dB];
      const int jeB = boff[dB + 1];
      float accA = 0.0f, accB = 0.0f;
      while (jA + 8 <= jeA && jB + 8 <= jeB) {
        float va[8], vb[8];
#pragma unroll
        for (int u = 0; u < 8; ++u)
          va[u] = x[(size_t)(sval[jA + u] >> BSHIFT) * IN_CH + k];
#pragma unroll
        for (int u = 0; u < 8; ++u)
          vb[u] = x[(size_t)(sval[jB + u] >> BSHIFT) * IN_CH + k];
        accA += ((va[0] + va[1]) + (va[2] + va[3])) +
                ((va[4] + va[5]) + (va[6] + va[7]));
        accB += ((vb[0] + vb[1]) + (vb[2] + vb[3])) +
                ((vb[4] + vb[5]) + (vb[6] + vb[7]));
        jA += 8;
        jB += 8;
      }
      // drain A
      for (; jA + 8 <= jeA; jA += 8) {
        float va[8];
#pragma unroll
        for (int u = 0; u < 8; ++u)
          va[u] = x[(size_t)(sval[jA + u] >> BSHIFT) * IN_CH + k];
        accA += ((va[0] + va[1]) + (va[2] + va[3])) +
                ((va[4] + va[5]) + (va[6] + va[7]));
      }
      for (; jA < jeA; ++jA)
        accA += x[(size_t)(sval[jA] >> BSHIFT) * IN_CH + k];
      // drain B
      for (; jB + 8 <= jeB; jB += 8) {
        float vb[8];
#pragma unroll
        for (int u = 0; u < 8; ++u)
          vb[u] = x[(size_t)(sval[jB + u] >> BSHIFT) * IN_CH + k];
        accB += ((vb[0] + vb[1]) + (vb[2] + vb[3])) +
                ((vb[4] + vb[5]) + (vb[6] + vb[7]));
      }
      for (; jB < jeB; ++jB)
        accB += x[(size_t)(sval[jB] >> BSHIFT) * IN_CH + k];
      sacc[dA * IN_CH + k] += accA;   // owner-exclusive, plain RMW
      sacc[dB * IN_CH + k] += accB;
    }
    __syncthreads();
  }
  // write mean rows: subgroup sub writes its 8 owned nodes, coalesced 128B
  const int node0 = b << BSHIFT;
  for (int dd = 0; dd < 8; ++dd) {
    const int d = (sub << 3) + dd;
    const int node = node0 + d;
    if (node < n)
      agg[(size_t)node * IN_CH + k] =
          sacc[d * IN_CH + k] / fmaxf((float)sdeg[d], 1.0f);
  }
}

// ---------------------------------------------------------------------------
// E: register-tiled fp32 GEMM:  out = [x | agg] @ [Wr ; Wl]^T + b (proven)
// ---------------------------------------------------------------------------
#define VS_LD 68

__global__ __launch_bounds__(256) void k_out(const float* __restrict__ x,
                                             const float* __restrict__ agg,
                                             const float* __restrict__ Wl,
                                             const float* __restrict__ Wr,
                                             const float* __restrict__ bl,
                                             float* __restrict__ out, int n) {
  __shared__ float ws[64 * 128];    // ws[k][c]: k<32 -> Wr[c][k], k>=32 -> Wl[c][k-32]
  __shared__ float vs[64 * VS_LD];  // vs[k][m]: k<32 -> x[node0+m][k], k>=32 -> agg[...]
  const int t = threadIdx.x;
  const int node0 = blockIdx.x << 6;

  const float4* wr4 = reinterpret_cast<const float4*>(Wr);
  const float4* wl4 = reinterpret_cast<const float4*>(Wl);
#pragma unroll
  for (int r = 0; r < 4; ++r) {
    int i = t + 256 * r;            // [0,1024): c = i>>3, k0 = (i&7)*4
    int c = i >> 3;
    int k0 = (i & 7) << 2;
    float4 a = wr4[i];
    float4 b = wl4[i];
    ws[(k0 + 0) * 128 + c] = a.x;
    ws[(k0 + 1) * 128 + c] = a.y;
    ws[(k0 + 2) * 128 + c] = a.z;
    ws[(k0 + 3) * 128 + c] = a.w;
    ws[(32 + k0 + 0) * 128 + c] = b.x;
    ws[(32 + k0 + 1) * 128 + c] = b.y;
    ws[(32 + k0 + 2) * 128 + c] = b.z;
    ws[(32 + k0 + 3) * 128 + c] = b.w;
  }

#pragma unroll
  for (int r = 0; r < 2; ++r) {
    int i = t + 256 * r;            // [0,512): m = i>>3, q = i&7
    int m = i >> 3;
    int q = i & 7;
    int k0 = q << 2;
    int node = node0 + m;
    float4 a = make_float4(0.f, 0.f, 0.f, 0.f);
    float4 b = make_float4(0.f, 0.f, 0.f, 0.f);
    if (node < n) {
      a = reinterpret_cast<const float4*>(x + (size_t)node * IN_CH)[q];
      b = reinterpret_cast<const float4*>(agg + (size_t)node * IN_CH)[q];
    }
    vs[(k0 + 0) * VS_LD + m] = a.x;
    vs[(k0 + 1) * VS_LD + m] = a.y;
    vs[(k0 + 2) * VS_LD + m] = a.z;
    vs[(k0 + 3) * VS_LD + m] = a.w;
    vs[(32 + k0 + 0) * VS_LD + m] = b.x;
    vs[(32 + k0 + 1) * VS_LD + m] = b.y;
    vs[(32 + k0 + 2) * VS_LD + m] = b.z;
    vs[(32 + k0 + 3) * VS_LD + m] = b.w;
  }

  const int c0 = (t & 31) << 2;     // 32 channel-groups of 4
  const int m0 = (t >> 5) << 3;     // 8 node-groups of 8
  const float4 bias = *reinterpret_cast<const float4*>(bl + c0);

  __syncthreads();

  float acc[8][4];
#pragma unroll
  for (int i = 0; i < 8; ++i)
#pragma unroll
    for (int j = 0; j < 4; ++j) acc[i][j] = 0.0f;

#pragma unroll 8
  for (int k = 0; k < 64; ++k) {
    float4 w  = *reinterpret_cast<const float4*>(&ws[k * 128 + c0]);
    float4 a0 = *reinterpret_cast<const float4*>(&vs[k * VS_LD + m0]);
    float4 a1 = *reinterpret_cast<const float4*>(&vs[k * VS_LD + m0 + 4]);
    float av[8] = {a0.x, a0.y, a0.z, a0.w, a1.x, a1.y, a1.z, a1.w};
#pragma unroll
    for (int i = 0; i < 8; ++i) {
      acc[i][0] += av[i] * w.x;
      acc[i][1] += av[i] * w.y;
      acc[i][2] += av[i] * w.z;
      acc[i][3] += av[i] * w.w;
    }
  }

#pragma unroll
  for (int i = 0; i < 8; ++i) {
    int node = node0 + m0 + i;
    if (node < n) {
      float4 o;
      o.x = acc[i][0] + bias.x;
      o.y = acc[i][1] + bias.y;
      o.z = acc[i][2] + bias.z;
      o.w = acc[i][3] + bias.w;
      *reinterpret_cast<float4*>(out + (size_t)node * OUT_CH + c0) = o;
    }
  }
}

extern "C" void kernel_launch(void* const* d_in, const int* in_sizes, int n_in,
                              void* d_out, int out_size, void* d_ws, size_t ws_size,
                              hipStream_t stream) {
  const float* x  = (const float*)d_in[0];
  const int*   ei = (const int*)d_in[1];   // [2, E] row-major int32
  const float* Wl = (const float*)d_in[2];
  const float* Wr = (const float*)d_in[3];
  const float* bl = (const float*)d_in[4];
  float* out = (float*)d_out;

  const int n_nodes = in_sizes[0] / IN_CH;
  const int n_edges = in_sizes[1] / 2;
  const int* src = ei;
  const int* dst = ei + n_edges;
  const int NB = (n_nodes + BW - 1) >> BSHIFT;   // 782

  // fixed-capacity slab per bucket: >= 2x the mean bucket load, pow2, min 4096
  int cap = 4096;
  const int mean2 = (int)(2 * ((long long)n_edges / (NB > 0 ? NB : 1)));
  while (cap < mean2) cap <<= 1;

  char* ws = (char*)d_ws;
  auto align16 = [](size_t v) { return (v + 15) & ~(size_t)15; };
  int* gcursor   = (int*)ws;       ws += align16(NB_P * 4);
  unsigned* part = (unsigned*)ws;  ws += align16((size_t)NB_P * cap * 4);
  float* agg     = (float*)ws;     ws += align16((size_t)n_nodes * IN_CH * 4);

  k_init<<<(NB_P + 511) / 512, 512, 0, stream>>>(gcursor, cap);
  k_partition<<<(n_edges + PCHUNK - 1) / PCHUNK, 256, 0, stream>>>(
      src, dst, gcursor, part, n_edges);
  k_agg<<<NB, 512, 0, stream>>>(x, part, gcursor, agg, n_nodes, cap);

  const int nblk_out = (n_nodes + 63) >> 6;      // 64-node tiles
  k_out<<<nblk_out, 256, 0, stream>>>(x, agg, Wl, Wr, bl, out, n_nodes);
}

// Round 6
// 103.116 us; speedup vs baseline: 1.0883x; 1.0883x over previous
//
#include <hip/hip_runtime.h>

#define IN_CH 32
#define OUT_CH 128
#define BSHIFT 7
#define BW 128          // nodes per bucket
#define NB_P 1024       // >= ceil(100000/128)=782
#define PCHUNK 2048     // edges per partition block
#define ACH 4096        // edges per k_agg sort-chunk (== slab cap: single pass)

// ---------------------------------------------------------------------------
// A: init per-bucket slab cursors: gcursor[b] = b*cap.
// ---------------------------------------------------------------------------
__global__ __launch_bounds__(512) void k_init(int* __restrict__ gcursor, int cap) {
  int i = blockIdx.x * 512 + threadIdx.x;
  if (i < NB_P) gcursor[i] = i * cap;
}

// ---------------------------------------------------------------------------
// C: partition with LDS reorder (unchanged, proven)
// ---------------------------------------------------------------------------
__global__ __launch_bounds__(256) void k_partition(const int* __restrict__ src,
                                                   const int* __restrict__ dst,
                                                   int* __restrict__ gcursor,
                                                   unsigned* __restrict__ part,
                                                   int E) {
  __shared__ int cnt[NB_P];
  __shared__ int lbase[NB_P];
  __shared__ int cur[NB_P];
  __shared__ int gbase[NB_P];
  __shared__ int ssum[256];
  __shared__ unsigned sval[PCHUNK];
  __shared__ int sadr[PCHUNK];
  const int t = threadIdx.x;
  const int base = blockIdx.x * PCHUNK;
  const int m = min(PCHUNK, E - base);
  for (int i = t; i < NB_P; i += 256) cnt[i] = 0;
  __syncthreads();
  int dl[8], sl[8];
#pragma unroll
  for (int u = 0; u < 8; ++u) {
    int i = t + 256 * u;
    dl[u] = -1;
    if (i < m) {
      dl[u] = dst[base + i];
      sl[u] = src[base + i];
      atomicAdd(&cnt[dl[u] >> BSHIFT], 1);
    }
  }
  __syncthreads();
  const int b4 = t * 4;
  int c0 = cnt[b4], c1 = cnt[b4 + 1], c2 = cnt[b4 + 2], c3 = cnt[b4 + 3];
  ssum[t] = c0 + c1 + c2 + c3;
  __syncthreads();
  for (int o = 1; o < 256; o <<= 1) {
    int a = (t >= o) ? ssum[t - o] : 0;
    __syncthreads();
    ssum[t] += a;
    __syncthreads();
  }
  int run = (t == 0) ? 0 : ssum[t - 1];
  lbase[b4] = run; cur[b4] = run; run += c0;
  lbase[b4 + 1] = run; cur[b4 + 1] = run; run += c1;
  lbase[b4 + 2] = run; cur[b4 + 2] = run; run += c2;
  lbase[b4 + 3] = run; cur[b4 + 3] = run;
  __syncthreads();
  for (int i = t; i < NB_P; i += 256)
    gbase[i] = cnt[i] ? atomicAdd(&gcursor[i], cnt[i]) : 0;
  __syncthreads();
#pragma unroll
  for (int u = 0; u < 8; ++u) {
    if (dl[u] >= 0) {
      int b = dl[u] >> BSHIFT;
      int p = atomicAdd(&cur[b], 1);
      sval[p] = ((unsigned)sl[u] << BSHIFT) | (unsigned)(dl[u] & (BW - 1));
      sadr[p] = gbase[b] + (p - lbase[b]);
    }
  }
  __syncthreads();
  for (int i = t; i < m; i += 256) part[sadr[i]] = sval[i];
}

// ---------------------------------------------------------------------------
// D: sorted owner-exclusive aggregation; 512 threads; subgroup owns 8 bins.
//    NEW gather scheme: 8 lanes cover one x row as float4s -> a 32-lane
//    subgroup loads 4 edges per global_load_dwordx4 (4x fewer load instrs),
//    16 edges in flight in 16 data VGPRs + 4 int32 saddr offsets (x indexed
//    as float4 with int index -> SGPR-base + 32-bit voffset addressing).
//    Cross-lane shfl_xor(8,16) reduce, lanes 0-7 do one float4 LDS RMW/bin.
//    ACH=4096 == slab cap: exactly one sort pass per bucket.
// ---------------------------------------------------------------------------
__global__ __launch_bounds__(512, 8) void k_agg(const float* __restrict__ x,
                                                const unsigned* __restrict__ part,
                                                const int* __restrict__ gcursor,
                                                float* __restrict__ agg, int n,
                                                int cap) {
  __shared__ float sacc[BW * IN_CH];   // 16 KB, owner-exclusive RMW
  __shared__ int sdeg[BW];
  __shared__ int hcnt[BW];
  __shared__ int ssc[BW];
  __shared__ int boff[BW + 1];
  __shared__ int cur[BW];
  __shared__ unsigned sval[ACH];       // 16 KB sorted chunk
  const int t = threadIdx.x;
  const int sub = t >> 5;   // 16 subgroups of 32 lanes
  const int k = t & 31;     // lane within subgroup
#pragma unroll
  for (int i = 0; i < 8; ++i) sacc[t + 512 * i] = 0.0f;
  if (t < BW) sdeg[t] = 0;
  __syncthreads();
  const int b = blockIdx.x;
  const int e0 = b * cap;
  const int cn = gcursor[b] - e0;

  const float4* __restrict__ x4 = reinterpret_cast<const float4*>(x);
  const int eg = k >> 3;   // edge slot 0..3
  const int c4 = k & 7;    // float4 channel group 0..7

  for (int base = 0; base < cn; base += ACH) {
    const int m = min(ACH, cn - base);
    if (t < BW) hcnt[t] = 0;
    __syncthreads();
    unsigned ev[8];
#pragma unroll
    for (int u = 0; u < 8; ++u) {
      int i = t + 512 * u;
      ev[u] = 0xFFFFFFFFu;
      if (i < m) {
        ev[u] = part[e0 + base + i];
        atomicAdd(&hcnt[ev[u] & (BW - 1)], 1);
      }
    }
    __syncthreads();
    if (t < BW) ssc[t] = hcnt[t];
    __syncthreads();
    for (int o = 1; o < BW; o <<= 1) {
      int a = (t >= o && t < BW) ? ssc[t - o] : 0;
      __syncthreads();
      if (t < BW) ssc[t] += a;
      __syncthreads();
    }
    if (t < BW) {
      int excl = (t == 0) ? 0 : ssc[t - 1];
      boff[t] = excl;
      cur[t] = excl;
      sdeg[t] += hcnt[t];
    }
    if (t == 0) boff[BW] = m;
    __syncthreads();
#pragma unroll
    for (int u = 0; u < 8; ++u) {
      if (ev[u] != 0xFFFFFFFFu) {
        int dl = ev[u] & (BW - 1);
        int p = atomicAdd(&cur[dl], 1);
        sval[p] = ev[u];
      }
    }
    __syncthreads();
    // owner-exclusive segmented reduction: subgroup sub owns bins [8s, 8s+8)
    for (int dd = 0; dd < 8; ++dd) {
      const int d = (sub << 3) + dd;
      int j = boff[d];
      const int je = boff[d + 1];
      if (j >= je) continue;
      float ax = 0.f, ay = 0.f, az = 0.f, aw = 0.f;
      for (; j < je; j += 16) {
        float4 v0 = make_float4(0.f, 0.f, 0.f, 0.f);
        float4 v1 = v0, v2 = v0, v3 = v0;
        const int i0 = j + eg;
        const int i1 = j + 4 + eg;
        const int i2 = j + 8 + eg;
        const int i3 = j + 12 + eg;
        if (i0 < je) v0 = x4[(int)(sval[i0] >> BSHIFT) * 8 + c4];
        if (i1 < je) v1 = x4[(int)(sval[i1] >> BSHIFT) * 8 + c4];
        if (i2 < je) v2 = x4[(int)(sval[i2] >> BSHIFT) * 8 + c4];
        if (i3 < je) v3 = x4[(int)(sval[i3] >> BSHIFT) * 8 + c4];
        ax += (v0.x + v1.x) + (v2.x + v3.x);
        ay += (v0.y + v1.y) + (v2.y + v3.y);
        az += (v0.z + v1.z) + (v2.z + v3.z);
        aw += (v0.w + v1.w) + (v2.w + v3.w);
      }
      // reduce over the 4 edge slots (lane xor 8, 16 stays in subgroup)
      ax += __shfl_xor(ax, 8);  ax += __shfl_xor(ax, 16);
      ay += __shfl_xor(ay, 8);  ay += __shfl_xor(ay, 16);
      az += __shfl_xor(az, 8);  az += __shfl_xor(az, 16);
      aw += __shfl_xor(aw, 8);  aw += __shfl_xor(aw, 16);
      if (k < 8) {
        float4* sp = reinterpret_cast<float4*>(&sacc[d * IN_CH + 4 * k]);
        float4 s = *sp;
        s.x += ax; s.y += ay; s.z += az; s.w += aw;
        *sp = s;                         // owner-exclusive, plain RMW
      }
    }
    __syncthreads();
  }
  // write mean rows: subgroup sub writes its 8 owned nodes, coalesced 128B
  const int node0 = b << BSHIFT;
  for (int dd = 0; dd < 8; ++dd) {
    const int d = (sub << 3) + dd;
    const int node = node0 + d;
    if (node < n)
      agg[(size_t)node * IN_CH + k] =
          sacc[d * IN_CH + k] / fmaxf((float)sdeg[d], 1.0f);
  }
}

// ---------------------------------------------------------------------------
// E: register-tiled fp32 GEMM:  out = [x | agg] @ [Wr ; Wl]^T + b (proven)
// ---------------------------------------------------------------------------
#define VS_LD 68

__global__ __launch_bounds__(256) void k_out(const float* __restrict__ x,
                                             const float* __restrict__ agg,
                                             const float* __restrict__ Wl,
                                             const float* __restrict__ Wr,
                                             const float* __restrict__ bl,
                                             float* __restrict__ out, int n) {
  __shared__ float ws[64 * 128];    // ws[k][c]: k<32 -> Wr[c][k], k>=32 -> Wl[c][k-32]
  __shared__ float vs[64 * VS_LD];  // vs[k][m]: k<32 -> x[node0+m][k], k>=32 -> agg[...]
  const int t = threadIdx.x;
  const int node0 = blockIdx.x << 6;

  const float4* wr4 = reinterpret_cast<const float4*>(Wr);
  const float4* wl4 = reinterpret_cast<const float4*>(Wl);
#pragma unroll
  for (int r = 0; r < 4; ++r) {
    int i = t + 256 * r;            // [0,1024): c = i>>3, k0 = (i&7)*4
    int c = i >> 3;
    int k0 = (i & 7) << 2;
    float4 a = wr4[i];
    float4 b = wl4[i];
    ws[(k0 + 0) * 128 + c] = a.x;
    ws[(k0 + 1) * 128 + c] = a.y;
    ws[(k0 + 2) * 128 + c] = a.z;
    ws[(k0 + 3) * 128 + c] = a.w;
    ws[(32 + k0 + 0) * 128 + c] = b.x;
    ws[(32 + k0 + 1) * 128 + c] = b.y;
    ws[(32 + k0 + 2) * 128 + c] = b.z;
    ws[(32 + k0 + 3) * 128 + c] = b.w;
  }

#pragma unroll
  for (int r = 0; r < 2; ++r) {
    int i = t + 256 * r;            // [0,512): m = i>>3, q = i&7
    int m = i >> 3;
    int q = i & 7;
    int k0 = q << 2;
    int node = node0 + m;
    float4 a = make_float4(0.f, 0.f, 0.f, 0.f);
    float4 b = make_float4(0.f, 0.f, 0.f, 0.f);
    if (node < n) {
      a = reinterpret_cast<const float4*>(x + (size_t)node * IN_CH)[q];
      b = reinterpret_cast<const float4*>(agg + (size_t)node * IN_CH)[q];
    }
    vs[(k0 + 0) * VS_LD + m] = a.x;
    vs[(k0 + 1) * VS_LD + m] = a.y;
    vs[(k0 + 2) * VS_LD + m] = a.z;
    vs[(k0 + 3) * VS_LD + m] = a.w;
    vs[(32 + k0 + 0) * VS_LD + m] = b.x;
    vs[(32 + k0 + 1) * VS_LD + m] = b.y;
    vs[(32 + k0 + 2) * VS_LD + m] = b.z;
    vs[(32 + k0 + 3) * VS_LD + m] = b.w;
  }

  const int c0 = (t & 31) << 2;     // 32 channel-groups of 4
  const int m0 = (t >> 5) << 3;     // 8 node-groups of 8
  const float4 bias = *reinterpret_cast<const float4*>(bl + c0);

  __syncthreads();

  float acc[8][4];
#pragma unroll
  for (int i = 0; i < 8; ++i)
#pragma unroll
    for (int j = 0; j < 4; ++j) acc[i][j] = 0.0f;

#pragma unroll 8
  for (int k = 0; k < 64; ++k) {
    float4 w  = *reinterpret_cast<const float4*>(&ws[k * 128 + c0]);
    float4 a0 = *reinterpret_cast<const float4*>(&vs[k * VS_LD + m0]);
    float4 a1 = *reinterpret_cast<const float4*>(&vs[k * VS_LD + m0 + 4]);
    float av[8] = {a0.x, a0.y, a0.z, a0.w, a1.x, a1.y, a1.z, a1.w};
#pragma unroll
    for (int i = 0; i < 8; ++i) {
      acc[i][0] += av[i] * w.x;
      acc[i][1] += av[i] * w.y;
      acc[i][2] += av[i] * w.z;
      acc[i][3] += av[i] * w.w;
    }
  }

#pragma unroll
  for (int i = 0; i < 8; ++i) {
    int node = node0 + m0 + i;
    if (node < n) {
      float4 o;
      o.x = acc[i][0] + bias.x;
      o.y = acc[i][1] + bias.y;
      o.z = acc[i][2] + bias.z;
      o.w = acc[i][3] + bias.w;
      *reinterpret_cast<float4*>(out + (size_t)node * OUT_CH + c0) = o;
    }
  }
}

extern "C" void kernel_launch(void* const* d_in, const int* in_sizes, int n_in,
                              void* d_out, int out_size, void* d_ws, size_t ws_size,
                              hipStream_t stream) {
  const float* x  = (const float*)d_in[0];
  const int*   ei = (const int*)d_in[1];   // [2, E] row-major int32
  const float* Wl = (const float*)d_in[2];
  const float* Wr = (const float*)d_in[3];
  const float* bl = (const float*)d_in[4];
  float* out = (float*)d_out;

  const int n_nodes = in_sizes[0] / IN_CH;
  const int n_edges = in_sizes[1] / 2;
  const int* src = ei;
  const int* dst = ei + n_edges;
  const int NB = (n_nodes + BW - 1) >> BSHIFT;   // 782

  // fixed-capacity slab per bucket: >= 2x the mean bucket load, pow2, min 4096
  int cap = 4096;
  const int mean2 = (int)(2 * ((long long)n_edges / (NB > 0 ? NB : 1)));
  while (cap < mean2) cap <<= 1;

  char* ws = (char*)d_ws;
  auto align16 = [](size_t v) { return (v + 15) & ~(size_t)15; };
  int* gcursor   = (int*)ws;       ws += align16(NB_P * 4);
  unsigned* part = (unsigned*)ws;  ws += align16((size_t)NB_P * cap * 4);
  float* agg     = (float*)ws;     ws += align16((size_t)n_nodes * IN_CH * 4);

  k_init<<<(NB_P + 511) / 512, 512, 0, stream>>>(gcursor, cap);
  k_partition<<<(n_edges + PCHUNK - 1) / PCHUNK, 256, 0, stream>>>(
      src, dst, gcursor, part, n_edges);
  k_agg<<<NB, 512, 0, stream>>>(x, part, gcursor, agg, n_nodes, cap);

  const int nblk_out = (n_nodes + 63) >> 6;      // 64-node tiles
  k_out<<<nblk_out, 256, 0, stream>>>(x, agg, Wl, Wr, bl, out, n_nodes);
}